// Round 5
// baseline (206.512 us; speedup 1.0000x reference)
//
#include <hip/hip_runtime.h>
#include <hip/hip_bf16.h>
#include <math.h>

#define DIM 512
#define NHEAD 8
#define HD 64
#define NBANK 4096
#define NQROWS 4096
#define EPS 1e-5f
#define QSCALE 0.125f
#define PART_ELEMS (NQROWS * DIM)   // one O-partial buffer (bf16 elems)

typedef __attribute__((ext_vector_type(4))) float floatx4;
typedef __attribute__((ext_vector_type(8))) short short8;

__device__ __forceinline__ unsigned short f2bf(float f) {
    unsigned int u = __float_as_uint(f);
    u += 0x7fffu + ((u >> 16) & 1u);          // round-to-nearest-even
    return (unsigned short)(u >> 16);
}
__device__ __forceinline__ float bf2f(unsigned short h) {
    return __uint_as_float(((unsigned int)h) << 16);
}
// packed fp32x2 -> bf16x2 (v_cvt_pk_bf16_f32), low short = a
__device__ __forceinline__ unsigned int pk2(float a, float b) {
    union { __hip_bfloat162 h; unsigned int u; } cvt;
    cvt.h = __float22bfloat162_rn(make_float2(a, b));
    return cvt.u;
}

// ---------------------------------------------------------------------------
// qkv_kernel: fused bf16-MFMA projections, 64x128 tiles.  (unchanged R4)
// ---------------------------------------------------------------------------
__global__ __launch_bounds__(256) void qkv_kernel(
    const float* __restrict__ xq, const float* __restrict__ xk, const float* __restrict__ xv,
    const float* __restrict__ Wqp, const float* __restrict__ Wkp, const float* __restrict__ Wvp,
    const float* __restrict__ qg, const float* __restrict__ qbeta,
    const float* __restrict__ kg, const float* __restrict__ kbeta,
    unsigned short* __restrict__ Qb, unsigned short* __restrict__ Kb,
    unsigned short* __restrict__ VTb)
{
    __shared__ short8 smem[1536];   // A [0,512)=64x64, B [512,1536)=128x64 (24 KB)
    short8* as = smem;
    short8* bs = smem + 512;
    const int tid  = threadIdx.x;
    const int w    = tid >> 6, lane = tid & 63, m = lane & 15, q = lane >> 4;
    const int wr   = w & 1, wc = w >> 1;
    const int row0 = blockIdx.x * 64;
    const int mat  = blockIdx.y >> 2;
    const int col0 = (blockIdx.y & 3) * 128;
    const float* X = (mat == 0) ? xq : (mat == 1) ? xk : xv;
    const float* W = (mat == 0) ? Wqp : (mat == 1) ? Wkp : Wvp;

    floatx4 acc[2][4];
    #pragma unroll
    for (int mt = 0; mt < 2; ++mt)
        #pragma unroll
        for (int nt = 0; nt < 4; ++nt) acc[mt][nt] = (floatx4){0.f, 0.f, 0.f, 0.f};

    for (int k0 = 0; k0 < DIM; k0 += 64) {
        #pragma unroll
        for (int p = 0; p < 6; ++p) {     // 512 A items + 1024 B items
            const int idx = tid + p * 256;
            if (idx < 512) {
                const int row = idx >> 3, seg = idx & 7;
                const float4* pa = (const float4*)(X + (size_t)(row0 + row) * DIM + k0 + seg * 8);
                const float4 a0 = pa[0], a1 = pa[1];
                union { short8 v; unsigned int u[4]; } ta;
                ta.u[0] = pk2(a0.x, a0.y); ta.u[1] = pk2(a0.z, a0.w);
                ta.u[2] = pk2(a1.x, a1.y); ta.u[3] = pk2(a1.z, a1.w);
                as[row * 8 + (seg ^ (row & 7))] = ta.v;
            } else {
                const int j = idx - 512;
                const int row = j >> 3, seg = j & 7;
                const float4* pb = (const float4*)(W + (size_t)(col0 + row) * DIM + k0 + seg * 8);
                const float4 b0 = pb[0], b1 = pb[1];
                union { short8 v; unsigned int u[4]; } tb;
                tb.u[0] = pk2(b0.x, b0.y); tb.u[1] = pk2(b0.z, b0.w);
                tb.u[2] = pk2(b1.x, b1.y); tb.u[3] = pk2(b1.z, b1.w);
                bs[row * 8 + (seg ^ (row & 7))] = tb.v;
            }
        }
        __syncthreads();
        #pragma unroll
        for (int s = 0; s < 2; ++s) {
            short8 af[2], bfr[4];
            #pragma unroll
            for (int mt = 0; mt < 2; ++mt)
                af[mt] = as[(wr * 32 + mt * 16 + m) * 8 + ((s * 4 + q) ^ (m & 7))];
            #pragma unroll
            for (int nt = 0; nt < 4; ++nt)
                bfr[nt] = bs[(wc * 64 + nt * 16 + m) * 8 + ((s * 4 + q) ^ (m & 7))];
            #pragma unroll
            for (int mt = 0; mt < 2; ++mt)
                #pragma unroll
                for (int nt = 0; nt < 4; ++nt)
                    acc[mt][nt] = __builtin_amdgcn_mfma_f32_16x16x32_bf16(af[mt], bfr[nt], acc[mt][nt], 0, 0, 0);
        }
        __syncthreads();
    }

    if (mat < 2) {
        const float* g = (mat == 0) ? qg : kg;
        const float* be = (mat == 0) ? qbeta : kbeta;
        unsigned short* Y = (mat == 0) ? Qb : Kb;
        float gv[4], bv[4];
        #pragma unroll
        for (int nt = 0; nt < 4; ++nt) { gv[nt] = g[nt * 16 + m]; bv[nt] = be[nt * 16 + m]; }
        #pragma unroll
        for (int mt = 0; mt < 2; ++mt) {
            #pragma unroll
            for (int r = 0; r < 4; ++r) {
                float s = 0.f, sq = 0.f;
                #pragma unroll
                for (int nt = 0; nt < 4; ++nt) { const float v = acc[mt][nt][r]; s += v; sq += v * v; }
                s  += __shfl_xor(s, 1);  s  += __shfl_xor(s, 2);  s  += __shfl_xor(s, 4);  s  += __shfl_xor(s, 8);
                sq += __shfl_xor(sq, 1); sq += __shfl_xor(sq, 2); sq += __shfl_xor(sq, 4); sq += __shfl_xor(sq, 8);
                const float mean = s * (1.f / HD);
                const float var  = sq * (1.f / HD) - mean * mean;
                const float rr   = rsqrtf(var + EPS);
                const int grow = row0 + wr * 32 + mt * 16 + q * 4 + r;
                #pragma unroll
                for (int nt = 0; nt < 4; ++nt) {
                    float v = (acc[mt][nt][r] - mean) * rr * gv[nt] + bv[nt];
                    if (mat == 0) v *= QSCALE;
                    Y[(size_t)grow * DIM + col0 + wc * 64 + nt * 16 + m] = f2bf(v);
                }
            }
        }
    } else {
        unsigned short* vt = (unsigned short*)smem;
        #pragma unroll
        for (int mt = 0; mt < 2; ++mt)
            #pragma unroll
            for (int nt = 0; nt < 4; ++nt) {
                const int c  = wc * 64 + nt * 16 + m;
                const int rw = wr * 32 + mt * 16 + q * 4;
                *(unsigned int*)(vt + c * 88 + rw)     = pk2(acc[mt][nt][0], acc[mt][nt][1]);
                *(unsigned int*)(vt + c * 88 + rw + 2) = pk2(acc[mt][nt][2], acc[mt][nt][3]);
            }
        __syncthreads();
        #pragma unroll
        for (int p = 0; p < 4; ++p) {
            const int idx = tid + p * 256;      // 1024 items = 128 cols x 8
            const int c = idx >> 3, sg = idx & 7;
            *(short8*)(VTb + (size_t)(col0 + c) * NBANK + row0 + sg * 8) =
                *(const short8*)(vt + c * 88 + sg * 8);
        }
    }
}

// ---------------------------------------------------------------------------
// attn_kernel: MFMA-bf16 flash attention, no-max softmax, split-4 over bank.
// NEW: computes S^T = mfma(K,Q) so P stays in registers; the C-reg(n=Qd*4+r)
// vs B-frag(n=Qd*8+j) mismatch is absorbed by BIT-PERMUTED V staging
// (y[5]=x[5], y[4]=x[2], y[3:2]=x[4:3], y[1:0]=x[1:0]) -- zero LDS P traffic.
// Block = 1 head x 128 q-rows, 4 waves x 32 rows; O^T epilogue transposes
// through the dead K/V LDS for coalesced b128 partial stores.
// ---------------------------------------------------------------------------
__global__ __launch_bounds__(256) void attn_kernel(
    const unsigned short* __restrict__ Qb, const unsigned short* __restrict__ Kb,
    const unsigned short* __restrict__ VTb, unsigned short* __restrict__ AOp,
    float* __restrict__ sums)
{
    __shared__ short8 smem[1024];       // 16 KB: ks [0,512), vts [512,1024)
    short8* ks  = smem;
    short8* vts = smem + 512;
    const int tid  = threadIdx.x;
    const int w    = tid >> 6;
    const int lane = tid & 63;
    const int m    = lane & 15;
    const int Qd   = lane >> 4;
    const int h    = blockIdx.x & 7;
    const int qg   = blockIdx.x >> 3;        // 0..31
    const int row0 = qg * 128;
    const int part = blockIdx.y;
    const int base0 = part * 1024;

    // Q B-operand frags: rows q = row0 + w*32 + mt*16 + m, k = s*32+Qd*8+j
    short8 qf[2][2];
    #pragma unroll
    for (int mt = 0; mt < 2; ++mt)
        #pragma unroll
        for (int s = 0; s < 2; ++s)
            qf[mt][s] = *(const short8*)(Qb + (size_t)(row0 + w * 32 + mt * 16 + m) * DIM
                                         + h * HD + s * 32 + Qd * 8);

    floatx4 of[4][2];                    // [d-tile t2][q-group mt], O^T
    float sump[2] = {0.f, 0.f};
    #pragma unroll
    for (int t = 0; t < 4; ++t)
        #pragma unroll
        for (int mt = 0; mt < 2; ++mt) of[t][mt] = (floatx4){0.f, 0.f, 0.f, 0.f};

    for (int base = base0; base < base0 + 1024; base += 64) {
        __syncthreads();
        // ---- stage K (natural order) ----
        #pragma unroll
        for (int it = 0; it < 2; ++it) {
            const int idx = tid + it * 256;
            const int n = idx >> 3, seg = idx & 7;
            ks[n * 8 + (seg ^ (n & 7))] =
                *(const short8*)(Kb + (size_t)(base + n) * DIM + h * HD + seg * 8);
        }
        // ---- stage V^T bit-permuted: slot (d, g, j) = V[base + y] with
        //      y = (g>>2)*32 + (g&3)*4 + (j<4 ? j : 16+(j&3)) ----
        #pragma unroll
        for (int it = 0; it < 2; ++it) {
            const int idx = tid + it * 256;
            const int d = idx >> 3, g = idx & 7;
            const unsigned short* vp = VTb + (size_t)(h * HD + d) * NBANK + base
                                       + (g >> 2) * 32 + (g & 3) * 4;
            const ushort4 lo = *(const ushort4*)(vp);
            const ushort4 hi = *(const ushort4*)(vp + 16);
            union { short8 v; ushort4 h4[2]; } tv;
            tv.h4[0] = lo; tv.h4[1] = hi;
            vts[d * 8 + (g ^ (d & 7))] = tv.v;
        }
        __syncthreads();

        // ---- S^T = K Q^T : lane holds S[n=t*16+Qd*4+r][q=mt*16+m] ----
        floatx4 st[4][2];
        #pragma unroll
        for (int t = 0; t < 4; ++t)
            #pragma unroll
            for (int mt = 0; mt < 2; ++mt) st[t][mt] = (floatx4){0.f, 0.f, 0.f, 0.f};
        #pragma unroll
        for (int s = 0; s < 2; ++s)
            #pragma unroll
            for (int t = 0; t < 4; ++t) {
                const short8 kf = ks[(t * 16 + m) * 8 + ((s * 4 + Qd) ^ (m & 7))];
                #pragma unroll
                for (int mt = 0; mt < 2; ++mt)
                    st[t][mt] = __builtin_amdgcn_mfma_f32_16x16x32_bf16(kf, qf[mt][s], st[t][mt], 0, 0, 0);
            }

        // ---- P = exp(S^T) in regs; row-sum partials; pack B-frags ----
        float p[4][2][4];
        #pragma unroll
        for (int t = 0; t < 4; ++t)
            #pragma unroll
            for (int mt = 0; mt < 2; ++mt)
                #pragma unroll
                for (int r = 0; r < 4; ++r) {
                    const float e = __expf(st[t][mt][r]);
                    p[t][mt][r] = e;
                    sump[mt] += e;
                }
        union { short8 v; unsigned int u[4]; } pf[2][2];   // [mt][s2]
        #pragma unroll
        for (int mt = 0; mt < 2; ++mt)
            #pragma unroll
            for (int s2 = 0; s2 < 2; ++s2)
                #pragma unroll
                for (int u = 0; u < 4; ++u)
                    pf[mt][s2].u[u] = pk2(p[s2 * 2 + (u >> 1)][mt][(u & 1) * 2],
                                          p[s2 * 2 + (u >> 1)][mt][(u & 1) * 2 + 1]);

        // ---- O^T += V^T P : vf rows d, pf rows q ----
        #pragma unroll
        for (int s2 = 0; s2 < 2; ++s2)
            #pragma unroll
            for (int t2 = 0; t2 < 4; ++t2) {
                const short8 vf = vts[(t2 * 16 + m) * 8 + ((s2 * 4 + Qd) ^ (m & 7))];
                #pragma unroll
                for (int mt = 0; mt < 2; ++mt)
                    of[t2][mt] = __builtin_amdgcn_mfma_f32_16x16x32_bf16(vf, pf[mt][s2].v, of[t2][mt], 0, 0, 0);
            }
    }

    // ---- denominators: reduce per-lane partials across quads ----
    #pragma unroll
    for (int mt = 0; mt < 2; ++mt) {
        float s = sump[mt];
        s += __shfl_xor(s, 16);
        s += __shfl_xor(s, 32);
        sump[mt] = s;                    // total for q = row0+w*32+mt*16+m
    }
    if (Qd == 0) {
        #pragma unroll
        for (int mt = 0; mt < 2; ++mt)
            sums[((size_t)part * NQROWS + row0 + w * 32 + mt * 16 + m) * NHEAD + h] = sump[mt];
    }

    // ---- O^T -> O via LDS (smem dead), coalesced bf16 b128 stores ----
    __syncthreads();
    unsigned int* ob = (unsigned int*)smem;   // O[q 0..127][d/2 0..31] u32-pairs
    #pragma unroll
    for (int t2 = 0; t2 < 4; ++t2)
        #pragma unroll
        for (int mt = 0; mt < 2; ++mt) {
            const int q  = w * 32 + mt * 16 + m;
            const int blk = t2 * 2 + (Qd >> 1);            // 16B block in row
            const int sub = (Qd & 1) * 2;
            const int bs  = (blk ^ (q & 7)) * 4;
            ob[q * 32 + bs + sub]     = pk2(of[t2][mt][0], of[t2][mt][1]);
            ob[q * 32 + bs + sub + 1] = pk2(of[t2][mt][2], of[t2][mt][3]);
        }
    __syncthreads();
    #pragma unroll
    for (int pp = 0; pp < 4; ++pp) {
        const int idx = tid + pp * 256;        // 1024 = 128 q x 8 segs
        const int q = idx >> 3, sg = idx & 7;
        *(short8*)(AOp + (size_t)part * PART_ELEMS + (size_t)(row0 + q) * DIM + h * HD + sg * 8) =
            smem[q * 8 + (sg ^ (q & 7))];
    }
}

// ---------------------------------------------------------------------------
// combine_kernel: AO = (sum_p O_p) / (sum_p s_p), bf16 out; fused final-LN
// row stats.  (unchanged R4)
// ---------------------------------------------------------------------------
__global__ __launch_bounds__(256) void combine_kernel(
    const unsigned short* __restrict__ AOp, const float* __restrict__ sums,
    unsigned short* __restrict__ AO, float* __restrict__ meanv, float* __restrict__ rstdv)
{
    __shared__ float rs[256], rq[256];
    const int tid = threadIdx.x;
    const int row = blockIdx.x * 2 + (tid >> 7);
    const int t   = tid & 127;                 // 4 cols per thread
    const int h   = t >> 4;

    float stot = 0.f;
    #pragma unroll
    for (int p = 0; p < 4; ++p)
        stot += sums[((size_t)p * NQROWS + row) * NHEAD + h];

    float o[4] = {0.f, 0.f, 0.f, 0.f};
    #pragma unroll
    for (int p = 0; p < 4; ++p) {
        const ushort4 u = *(const ushort4*)(AOp + (size_t)p * PART_ELEMS + (size_t)row * DIM + t * 4);
        o[0] += bf2f(u.x); o[1] += bf2f(u.y); o[2] += bf2f(u.z); o[3] += bf2f(u.w);
    }
    const float inv = 1.0f / stot;
    float v0 = o[0] * inv, v1 = o[1] * inv, v2 = o[2] * inv, v3 = o[3] * inv;

    uint2 packed;
    packed.x = pk2(v0, v1); packed.y = pk2(v2, v3);
    *(uint2*)(AO + (size_t)row * DIM + t * 4) = packed;

    rs[tid] = v0 + v1 + v2 + v3;
    rq[tid] = v0 * v0 + v1 * v1 + v2 * v2 + v3 * v3;
    __syncthreads();
    #pragma unroll
    for (int off = 64; off > 0; off >>= 1) {
        if (t < off) { rs[tid] += rs[tid + off]; rq[tid] += rq[tid + off]; }
        __syncthreads();
    }
    if (t == 0) {
        const float mean = rs[tid] * (1.f / DIM);
        const float var  = rq[tid] * (1.f / DIM) - mean * mean;
        meanv[row] = mean;
        rstdv[row] = rsqrtf(var + EPS);
    }
}

// ---------------------------------------------------------------------------
// final_kernel: out = LN_512(AO) @ Wproj^T.  (unchanged R4)
// ---------------------------------------------------------------------------
__global__ __launch_bounds__(256) void final_kernel(
    const unsigned short* __restrict__ AO, const float* __restrict__ W,
    const float* __restrict__ meanv, const float* __restrict__ rstdv,
    const float* __restrict__ g, const float* __restrict__ be,
    float* __restrict__ out)
{
    __shared__ short8 fs[1024];            // A [0,512)=64x64, B [512,1024)=64x64
    __shared__ float gls[512], bls[512];
    const int tid  = threadIdx.x;
    const int w    = tid >> 6, lane = tid & 63, m = lane & 15, q = lane >> 4;
    const int row0 = blockIdx.x * 64;
    const int col0 = blockIdx.y * 64;

    #pragma unroll
    for (int i = 0; i < 2; ++i) { gls[tid + i * 256] = g[tid + i * 256]; bls[tid + i * 256] = be[tid + i * 256]; }

    floatx4 acc[4];
    #pragma unroll
    for (int mt = 0; mt < 4; ++mt) acc[mt] = (floatx4){0.f, 0.f, 0.f, 0.f};
    __syncthreads();

    for (int k0 = 0; k0 < DIM; k0 += 64) {
        #pragma unroll
        for (int p = 0; p < 4; ++p) {      // 512 A items + 512 B items
            const int idx = tid + p * 256;
            if (idx < 512) {
                const int row = idx >> 3, seg = idx & 7;
                const short8 a = *(const short8*)(AO + (size_t)(row0 + row) * DIM + k0 + seg * 8);
                const float mm = meanv[row0 + row], rr = rstdv[row0 + row];
                const float* gp = gls + k0 + seg * 8;
                const float* bp = bls + k0 + seg * 8;
                float v[8];
                #pragma unroll
                for (int j = 0; j < 8; ++j)
                    v[j] = (bf2f((unsigned short)a[j]) - mm) * rr * gp[j] + bp[j];
                union { short8 s; unsigned int u[4]; } ta;
                ta.u[0] = pk2(v[0], v[1]); ta.u[1] = pk2(v[2], v[3]);
                ta.u[2] = pk2(v[4], v[5]); ta.u[3] = pk2(v[6], v[7]);
                fs[row * 8 + (seg ^ (row & 7))] = ta.s;
            } else {
                const int j = idx - 512;
                const int row = j >> 3, seg = j & 7;
                const float4* pb = (const float4*)(W + (size_t)(col0 + row) * DIM + k0 + seg * 8);
                const float4 b0 = pb[0], b1 = pb[1];
                union { short8 s; unsigned int u[4]; } tb;
                tb.u[0] = pk2(b0.x, b0.y); tb.u[1] = pk2(b0.z, b0.w);
                tb.u[2] = pk2(b1.x, b1.y); tb.u[3] = pk2(b1.z, b1.w);
                fs[512 + row * 8 + (seg ^ (row & 7))] = tb.s;
            }
        }
        __syncthreads();
        #pragma unroll
        for (int s = 0; s < 2; ++s) {
            short8 af[4];
            #pragma unroll
            for (int mt = 0; mt < 4; ++mt)
                af[mt] = fs[(mt * 16 + m) * 8 + ((s * 4 + q) ^ (m & 7))];
            const short8 bfr = fs[512 + (w * 16 + m) * 8 + ((s * 4 + q) ^ (m & 7))];
            #pragma unroll
            for (int mt = 0; mt < 4; ++mt)
                acc[mt] = __builtin_amdgcn_mfma_f32_16x16x32_bf16(af[mt], bfr, acc[mt], 0, 0, 0);
        }
        __syncthreads();
    }

    #pragma unroll
    for (int mt = 0; mt < 4; ++mt)
        #pragma unroll
        for (int r = 0; r < 4; ++r)
            out[(size_t)(row0 + mt * 16 + q * 4 + r) * DIM + col0 + w * 16 + m] = acc[mt][r];
}

// ---------------------------------------------------------------------------
extern "C" void kernel_launch(void* const* d_in, const int* in_sizes, int n_in,
                              void* d_out, int out_size, void* d_ws, size_t ws_size,
                              hipStream_t stream)
{
    const float* x_q = (const float*)d_in[0];
    const float* x_k = (const float*)d_in[1];
    const float* x_v = (const float*)d_in[2];
    const float* Wq  = (const float*)d_in[3];
    const float* Wk  = (const float*)d_in[4];
    const float* Wv  = (const float*)d_in[5];
    const float* Wp  = (const float*)d_in[6];
    const float* qg  = (const float*)d_in[7];
    const float* qb  = (const float*)d_in[8];
    const float* kg  = (const float*)d_in[9];
    const float* kb  = (const float*)d_in[10];
    const float* ng  = (const float*)d_in[11];
    const float* nb  = (const float*)d_in[12];
    float* out = (float*)d_out;

    // ws: Qb|Kb|VTb (bf16, 4 MB each) | AOp (bf16, 4x4 MB) | sums 512 KB |
    //     stats 32 KB.  AO (bf16) aliases Qb (dead after attn). Total ~28.6 MB.
    unsigned short* Qb   = (unsigned short*)d_ws;
    unsigned short* Kb   = Qb  + (size_t)NQROWS * DIM;
    unsigned short* VTb  = Kb  + (size_t)NBANK * DIM;
    unsigned short* AOp  = VTb + (size_t)NBANK * DIM;
    float*          sums = (float*)(AOp + (size_t)4 * PART_ELEMS);
    float*          meanv = sums + (size_t)4 * NQROWS * NHEAD;
    float*          rstdv = meanv + NQROWS;
    unsigned short* AO   = Qb;   // alias: Qb dead after attn_kernel

    qkv_kernel<<<dim3(64, 12), 256, 0, stream>>>(x_q, x_k, x_v, Wq, Wk, Wv,
                                                 qg, qb, kg, kb, Qb, Kb, VTb);
    attn_kernel<<<dim3(256, 4), 256, 0, stream>>>(Qb, Kb, VTb, AOp, sums);
    combine_kernel<<<NQROWS / 2, 256, 0, stream>>>(AOp, sums, AO, meanv, rstdv);
    final_kernel<<<dim3(64, 8), 256, 0, stream>>>(AO, Wp, meanv, rstdv, ng, nb, out);
}